// Round 5
// baseline (554.290 us; speedup 1.0000x reference)
//
#include <hip/hip_runtime.h>
#include <math.h>

#define N_DIM 32
#define C_DIM 512
#define K_DIM 64
#define P_DIM 3136
#define PT 49          // p-tiles in k_logits (49 * 64 = 3136, exact)

// ws layout (floats): wt 32768 | a_t 6422528 | asum 2048 | apart 100352 |
//                     gsum 32 | ssb 16384 | part S*1048576
// base ~25.1 MB; S=14 -> 81.2 MB, S=7 -> 53.2 MB, S=2 -> 33.1 MB

// ---------------- prep: wt[c][k] = conv_w[k][c] ----------------
__global__ __launch_bounds__(256) void k_prep(const float* __restrict__ conv_w,
                                              float* __restrict__ wt) {
    const int b = blockIdx.x, t = threadIdx.x;
#pragma unroll
    for (int r = 0; r < 4; ++r) {
        int idx = b * 1024 + r * 256 + t;      // 0..32767
        int c = idx >> 6, k = idx & 63;
        wt[idx] = conv_w[k * C_DIM + c];
    }
}

// ---------------- GEMM1 + softmax + asum partials: a_t[n][p][k] ----------------
// block: 64 pixels x 64 k (49 exact tiles), 128 threads; thread: 4p x 8k.
// register-prefetch double buffering; a_t stored via LDS transpose (coalesced).
__global__ __launch_bounds__(128) void k_logits(const float* __restrict__ x,
                                                const float* __restrict__ wt,
                                                const float* __restrict__ bias,
                                                float* __restrict__ a_t,
                                                float* __restrict__ asum_part) {
    __shared__ float smem[4096 + 128];
    float (*xs)[64]  = (float (*)[64])smem;           // [32][64]  8 KB (c-chunk x pixel)
    float (*wsh)[64] = (float (*)[64])(smem + 2048);  // [32][64]  8 KB (c-chunk x k)
    float* tb  = smem;                                 // [64][64] 16 KB transpose buf (aliases)
    float* asl = smem + 4096;                          // [2][64]

    const int tid = threadIdx.x;
    const int n  = blockIdx.y;
    const int pt = blockIdx.x;
    const int p0 = pt * 64;
    const int tp = tid >> 3;        // 0..15 -> pixels p0 + tp + 16*i, i<4
    const int tk = tid & 7;         // 0..7  -> k = tk*8..+8

    float acc[4][8];
    {
        float4 b0 = *(const float4*)(bias + tk * 8);
        float4 b1 = *(const float4*)(bias + tk * 8 + 4);
        float br[8] = {b0.x, b0.y, b0.z, b0.w, b1.x, b1.y, b1.z, b1.w};
#pragma unroll
        for (int i = 0; i < 4; ++i)
#pragma unroll
            for (int j = 0; j < 8; ++j) acc[i][j] = br[j];
    }

    const float* xn = x + (size_t)n * C_DIM * P_DIM + p0;

    float4 xv[4], wv[4];
#pragma unroll
    for (int i = 0; i < 4; ++i) {
        int f = tid + 128 * i;                       // 0..511
        xv[i] = *(const float4*)(xn + (size_t)(f >> 4) * P_DIM + (f & 15) * 4);
        wv[i] = *(const float4*)(wt + (f >> 4) * K_DIM + (f & 15) * 4);
    }

    for (int cc = 0; cc < C_DIM; cc += 32) {
        __syncthreads();
#pragma unroll
        for (int i = 0; i < 4; ++i) {
            int f = tid + 128 * i;
            *(float4*)&xs[f >> 4][(f & 15) * 4] = xv[i];
            *(float4*)&wsh[f >> 4][(f & 15) * 4] = wv[i];
        }
        __syncthreads();

        if (cc + 32 < C_DIM) {
            const float* xc = xn + (size_t)(cc + 32) * P_DIM;
            const float* wc = wt + (cc + 32) * K_DIM;
#pragma unroll
            for (int i = 0; i < 4; ++i) {
                int f = tid + 128 * i;
                xv[i] = *(const float4*)(xc + (size_t)(f >> 4) * P_DIM + (f & 15) * 4);
                wv[i] = *(const float4*)(wc + (f >> 4) * K_DIM + (f & 15) * 4);
            }
        }

#pragma unroll 8
        for (int c = 0; c < 32; ++c) {
            float xr[4];
#pragma unroll
            for (int i = 0; i < 4; ++i) xr[i] = xs[c][tp + 16 * i];   // broadcast
            float4 w0 = *(const float4*)&wsh[c][tk * 8];
            float4 w1 = *(const float4*)&wsh[c][tk * 8 + 4];
            float wr[8] = {w0.x, w0.y, w0.z, w0.w, w1.x, w1.y, w1.z, w1.w};
#pragma unroll
            for (int i = 0; i < 4; ++i)
#pragma unroll
                for (int j = 0; j < 8; ++j)
                    acc[i][j] = fmaf(xr[i], wr[j], acc[i][j]);
        }
    }

    // softmax per pixel: 64 k live in the 8 lanes sharing tp (xor 1,2,4)
    float sk[8] = {0.f, 0.f, 0.f, 0.f, 0.f, 0.f, 0.f, 0.f};
#pragma unroll
    for (int i = 0; i < 4; ++i) {
        float m = acc[i][0];
#pragma unroll
        for (int j = 1; j < 8; ++j) m = fmaxf(m, acc[i][j]);
        m = fmaxf(m, __shfl_xor(m, 1));
        m = fmaxf(m, __shfl_xor(m, 2));
        m = fmaxf(m, __shfl_xor(m, 4));
        float s = 0.f;
#pragma unroll
        for (int j = 0; j < 8; ++j) { acc[i][j] = __expf(acc[i][j] - m); s += acc[i][j]; }
        s += __shfl_xor(s, 1);
        s += __shfl_xor(s, 2);
        s += __shfl_xor(s, 4);
        const float inv = 1.0f / s;
#pragma unroll
        for (int j = 0; j < 8; ++j) { acc[i][j] *= inv; sk[j] += acc[i][j]; }
    }
    // reduce sk over the 8 tp-lanes in this wave (bits 3,4,5)
#pragma unroll
    for (int j = 0; j < 8; ++j) {
        sk[j] += __shfl_xor(sk[j], 8);
        sk[j] += __shfl_xor(sk[j], 16);
        sk[j] += __shfl_xor(sk[j], 32);
    }

    __syncthreads();   // xs/wsh reads done -> safe to reuse as tb
#pragma unroll
    for (int i = 0; i < 4; ++i) {
        float* t = tb + (tp + 16 * i) * K_DIM + tk * 8;
        *(float4*)t       = make_float4(acc[i][0], acc[i][1], acc[i][2], acc[i][3]);
        *(float4*)(t + 4) = make_float4(acc[i][4], acc[i][5], acc[i][6], acc[i][7]);
    }
    const int lane = tid & 63, wvi = tid >> 6;
    if (lane < 8) {
#pragma unroll
        for (int j = 0; j < 8; ++j) asl[wvi * 64 + lane * 8 + j] = sk[j];
    }
    __syncthreads();

    // fully-coalesced a_t store: 64px x 64k contiguous block
    float* ab = a_t + ((size_t)n * P_DIM + p0) * K_DIM;
#pragma unroll
    for (int r = 0; r < 8; ++r) {
        int f = tid + 128 * r;                 // 0..1023 float4s
        *(float4*)(ab + 4 * f) = *(const float4*)(tb + 4 * f);
    }
    if (tid < 64)
        asum_part[((size_t)n * PT + pt) * K_DIM + tid] = asl[tid] + asl[64 + tid];
}

// ---------------- asum[n][k] = sum_b asum_part[n][b][k] ----------------
__global__ __launch_bounds__(256) void k_red(const float* __restrict__ asum_part,
                                             float* __restrict__ asum) {
    const int idx = blockIdx.x * 256 + threadIdx.x;   // 0..2047
    const int n = idx >> 6, k = idx & 63;
    float s = 0.f;
#pragma unroll
    for (int b = 0; b < PT; ++b)
        s += asum_part[((size_t)n * PT + b) * K_DIM + k];
    asum[idx] = s;
}

// ---------------- GEMM2: part[s][n][c][k] = sum_{p in slice} x[n][c][p]*a_t[n][p][k] ----
// block: 128c x 64k, 128 threads, 16c x 4k/thread (contiguous-row stores);
// register-prefetch double buffering over 16-p chunks.
__global__ __launch_bounds__(128) void k_gemm2(const float* __restrict__ x,
                                               const float* __restrict__ a_t,
                                               float* __restrict__ part,
                                               int pslice) {
    __shared__ float xs[16][132];   // [p][c], pad 128->132
    __shared__ float as[16][64];    // [p][k]
    const int tid = threadIdx.x;
    const int c0 = blockIdx.x * 128;
    const int n  = blockIdx.y;
    const int s  = blockIdx.z;
    const int p0 = s * pslice;
    const int tc  = tid >> 4;       // 0..7  -> c rows c0 + tc*16 + i, i<16
    const int tk4 = tid & 15;       // 0..15 -> k = tk4*4 + j, j<4

    float acc[16][4];
#pragma unroll
    for (int i = 0; i < 16; ++i)
#pragma unroll
        for (int j = 0; j < 4; ++j) acc[i][j] = 0.f;

    const float* xb = x + ((size_t)n * C_DIM + c0) * P_DIM + p0;
    const float* ab = a_t + ((size_t)n * P_DIM + p0) * K_DIM;

    float4 xv[4], av[2];
#pragma unroll
    for (int i = 0; i < 4; ++i) {
        int f = tid + 128 * i;
        xv[i] = *(const float4*)(xb + (size_t)(f >> 2) * P_DIM + (f & 3) * 4);
    }
#pragma unroll
    for (int i = 0; i < 2; ++i) {
        int f = tid + 128 * i;
        av[i] = *(const float4*)(ab + (size_t)(f >> 4) * K_DIM + (f & 15) * 4);
    }

    for (int pb = 0; pb < pslice; pb += 16) {
        __syncthreads();
#pragma unroll
        for (int i = 0; i < 4; ++i) {
            int f = tid + 128 * i;
            int c = f >> 2, pe = (f & 3) * 4;
            xs[pe + 0][c] = xv[i].x;
            xs[pe + 1][c] = xv[i].y;
            xs[pe + 2][c] = xv[i].z;
            xs[pe + 3][c] = xv[i].w;
        }
#pragma unroll
        for (int i = 0; i < 2; ++i) {
            int f = tid + 128 * i;
            *(float4*)&as[f >> 4][(f & 15) * 4] = av[i];
        }
        __syncthreads();

        if (pb + 16 < pslice) {
            const float* xc = xb + pb + 16;
            const float* ac = ab + (size_t)(pb + 16) * K_DIM;
#pragma unroll
            for (int i = 0; i < 4; ++i) {
                int f = tid + 128 * i;
                xv[i] = *(const float4*)(xc + (size_t)(f >> 2) * P_DIM + (f & 3) * 4);
            }
#pragma unroll
            for (int i = 0; i < 2; ++i) {
                int f = tid + 128 * i;
                av[i] = *(const float4*)(ac + (size_t)(f >> 4) * K_DIM + (f & 15) * 4);
            }
        }

#pragma unroll 4
        for (int p = 0; p < 16; ++p) {
            float4 a4 = *(const float4*)&as[p][tk4 * 4];
            float ar[4] = {a4.x, a4.y, a4.z, a4.w};
            float xr[16];
#pragma unroll
            for (int q = 0; q < 4; ++q) {
                float4 xq = *(const float4*)&xs[p][tc * 16 + q * 4];
                xr[q * 4 + 0] = xq.x; xr[q * 4 + 1] = xq.y;
                xr[q * 4 + 2] = xq.z; xr[q * 4 + 3] = xq.w;
            }
#pragma unroll
            for (int i = 0; i < 16; ++i)
#pragma unroll
                for (int j = 0; j < 4; ++j)
                    acc[i][j] = fmaf(xr[i], ar[j], acc[i][j]);
        }
    }

    // contiguous-row stores: lanes 0..15 cover one full 256B k-row
    float* po = part + (((size_t)s * N_DIM + n) * C_DIM + c0 + tc * 16) * K_DIM + tk4 * 4;
#pragma unroll
    for (int i = 0; i < 16; ++i) {
        *(float4*)&po[(size_t)i * K_DIM] =
            make_float4(acc[i][0], acc[i][1], acc[i][2], acc[i][3]);
    }
}

// ---------------- slice-reduce + subtract + intra-norm over k; ss -> ssb ----------------
template <int S>
__global__ __launch_bounds__(256) void k_intra(const float* __restrict__ part,
                                               const float* __restrict__ cent,
                                               const float* __restrict__ asum,
                                               float* __restrict__ out,
                                               float* __restrict__ ssb) {
    const int w = (blockIdx.x * 256 + threadIdx.x) >> 6;  // (n,c) wave id
    const int lane = threadIdx.x & 63;
    const int n = w >> 9;
    const int c = w & 511;
    const size_t off = ((size_t)n * C_DIM + c) * K_DIM + lane;
    const size_t stride = (size_t)N_DIM * C_DIM * K_DIM;

    float v = 0.f;
#pragma unroll
    for (int s = 0; s < S; ++s) v += part[s * stride + off];
    // cent_r[c][k] = centroids_flat[c*64 + k] (row-major reshape, NOT transpose)
    v -= cent[c * K_DIM + lane] * asum[n * K_DIM + lane];

    float ss = v * v;
#pragma unroll
    for (int o = 32; o > 0; o >>= 1) ss += __shfl_xor(ss, o);

    const float denom = fmaxf(sqrtf(ss), 1e-12f);
    out[off] = v / denom;
    if (lane == 0) ssb[w] = ss / (denom * denom);
}

// ---------------- gsum[n] = sum_c ssb[n][c] ----------------
__global__ __launch_bounds__(256) void k_gsum(const float* __restrict__ ssb,
                                              float* __restrict__ gsum) {
    const int n = blockIdx.x, t = threadIdx.x;
    float s = ssb[n * C_DIM + t] + ssb[n * C_DIM + t + 256];
    __shared__ float red[256];
    red[t] = s;
    __syncthreads();
    for (int o = 128; o > 0; o >>= 1) {
        if (t < o) red[t] += red[t + o];
        __syncthreads();
    }
    if (t == 0) gsum[n] = red[0];
}

// ---------------- final global L2 normalization ----------------
__global__ __launch_bounds__(256) void k_final(float* __restrict__ out,
                                               const float* __restrict__ gsum) {
    const size_t i = (size_t)blockIdx.x * 256 + threadIdx.x;  // 0 .. 2^20-1
    const int n = (int)(i >> 15);                             // C*K = 32768
    const float g = sqrtf(gsum[n]);
    out[i] = out[i] / fmaxf(g, 1e-12f);
}

extern "C" void kernel_launch(void* const* d_in, const int* in_sizes, int n_in,
                              void* d_out, int out_size, void* d_ws, size_t ws_size,
                              hipStream_t stream) {
    const float* x      = (const float*)d_in[0];  // (32,512,56,56)
    const float* cent   = (const float*)d_in[1];  // (64,512) flat
    const float* conv_w = (const float*)d_in[2];  // (64,512)
    const float* conv_b = (const float*)d_in[3];  // (64,)

    float* ws    = (float*)d_ws;
    float* wt    = ws;                                     // 32768
    float* a_t   = wt + 32768;                             // 32*3136*64
    float* asum  = a_t + (size_t)N_DIM * P_DIM * K_DIM;    // 2048
    float* apart = asum + 2048;                            // 32*49*64 = 100352
    float* gsum  = apart + (size_t)N_DIM * PT * K_DIM;     // 32
    float* ssb   = gsum + 32;                              // 16384
    float* part  = ssb + 16384;                            // S * 1048576
    float* out   = (float*)d_out;

    const size_t base_f = (size_t)(part - ws);
    const size_t cxk = (size_t)N_DIM * C_DIM * K_DIM;      // 1048576
    int S = 14;
    if (ws_size < (base_f + 14 * cxk) * 4) S = 7;
    if (ws_size < (base_f + 7 * cxk) * 4) S = 2;
    const int pslice = P_DIM / S;

    hipLaunchKernelGGL(k_prep,   dim3(32),        dim3(256), 0, stream, conv_w, wt);
    hipLaunchKernelGGL(k_logits, dim3(PT, 32),    dim3(128), 0, stream, x, wt, conv_b, a_t, apart);
    hipLaunchKernelGGL(k_red,    dim3(8),         dim3(256), 0, stream, apart, asum);
    hipLaunchKernelGGL(k_gemm2,  dim3(4, 32, S),  dim3(128), 0, stream, x, a_t, part, pslice);
    if (S == 14)
        hipLaunchKernelGGL(k_intra<14>, dim3(4096), dim3(256), 0, stream, part, cent, asum, out, ssb);
    else if (S == 7)
        hipLaunchKernelGGL(k_intra<7>,  dim3(4096), dim3(256), 0, stream, part, cent, asum, out, ssb);
    else
        hipLaunchKernelGGL(k_intra<2>,  dim3(4096), dim3(256), 0, stream, part, cent, asum, out, ssb);
    hipLaunchKernelGGL(k_gsum,   dim3(32),        dim3(256), 0, stream, ssb, gsum);
    hipLaunchKernelGGL(k_final,  dim3(4096),      dim3(256), 0, stream, out, gsum);
}